// Round 3
// baseline (1338.789 us; speedup 1.0000x reference)
//
#include <hip/hip_runtime.h>

static constexpr int BATCH = 131072;
static constexpr int SENSN = 61;
static constexpr int HIDN  = 64;
static constexpr int NSTEP = 10;
static constexpr int TPB   = 256;

// Repeat macro: M(0) .. M(63)
#define R64(M) \
  M(0) M(1) M(2) M(3) M(4) M(5) M(6) M(7) \
  M(8) M(9) M(10) M(11) M(12) M(13) M(14) M(15) \
  M(16) M(17) M(18) M(19) M(20) M(21) M(22) M(23) \
  M(24) M(25) M(26) M(27) M(28) M(29) M(30) M(31) \
  M(32) M(33) M(34) M(35) M(36) M(37) M(38) M(39) \
  M(40) M(41) M(42) M(43) M(44) M(45) M(46) M(47) \
  M(48) M(49) M(50) M(51) M(52) M(53) M(54) M(55) \
  M(56) M(57) M(58) M(59) M(60) M(61) M(62) M(63)

// tanh(x) = 1 - 2/(exp(2x)+1); exact saturation at +-inf, ~1e-7 abs error.
__device__ __forceinline__ float fast_tanh(float x) {
    float e = __expf(2.0f * x);                  // v_mul + v_exp_f32
    float r = __builtin_amdgcn_rcpf(e + 1.0f);   // v_add + v_rcp_f32
    return fmaf(-2.0f, r, 1.0f);
}

__global__ void __launch_bounds__(TPB, 2)
node_kernel(const float* __restrict__ pad0,
            const float* __restrict__ sens,
            const float* __restrict__ W1,
            const float* __restrict__ b1v,
            const float* __restrict__ W2,
            const float* __restrict__ b2v,
            const float* __restrict__ W3,
            const float* __restrict__ b3v,
            const float* __restrict__ scale_p,
            float* __restrict__ out)
{
    // S_lds[j][tid]: lanes read consecutive addresses -> 2 lanes/bank -> conflict-free.
    // Each thread touches only its own column -> no __syncthreads needed.
    __shared__ float S_lds[HIDN][TPB];

    const int tid = threadIdx.x;
    const int b   = blockIdx.x * TPB + tid;

    // ---- one-time: S[j] = b1[j] + sensory[b,:] @ W1[3:64,:] in named scalars ----
#define SDECL(j) float s_##j = b1v[j];
    R64(SDECL)
#undef SDECL
    {
        const float* __restrict__ srow = sens + (long)b * SENSN;
#pragma unroll 1
        for (int s = 0; s < SENSN; ++s) {
            const float xv = srow[s];
            const float* __restrict__ w = W1 + (3 + s) * HIDN;  // uniform -> s_load
#define SFMA(j) s_##j = fmaf(xv, w[j], s_##j);
            R64(SFMA)
#undef SFMA
        }
    }
#define SSTORE(j) S_lds[j][tid] = s_##j;
    R64(SSTORE)
#undef SSTORE

    float y0 = pad0[b * 3 + 0];
    float y1 = pad0[b * 3 + 1];
    float y2 = pad0[b * 3 + 2];
    const float scale = scale_p[0];
    const float h = 0.1f;

    // k1..k5 in scalars (k6 folded into the final combine)
    float k00=0,k01=0,k02=0, k10=0,k11=0,k12=0, k20=0,k21=0,k22=0,
          k30=0,k31=0,k32=0, k40=0,k41=0,k42=0;

#pragma unroll 1
    for (int step = 0; step < NSTEP; ++step) {
        const float t0 = (float)step * h;
#pragma unroll 1
        for (int st = 0; st < 6; ++st) {   // runtime loop: one copy of the MLP body
            float tt = t0, v0 = y0, v1 = y1, v2 = y2;
            switch (st) {                  // wave-uniform branch
            case 0: break;
            case 1: {
                const float a21 = (float)(1.0/5.0);
                v0 = fmaf(h, a21*k00, y0);
                v1 = fmaf(h, a21*k01, y1);
                v2 = fmaf(h, a21*k02, y2);
                tt = t0 + 0.2f*h;
            } break;
            case 2: {
                const float a31 = (float)(3.0/40.0), a32 = (float)(9.0/40.0);
                v0 = fmaf(h, a31*k00 + a32*k10, y0);
                v1 = fmaf(h, a31*k01 + a32*k11, y1);
                v2 = fmaf(h, a31*k02 + a32*k12, y2);
                tt = t0 + 0.3f*h;
            } break;
            case 3: {
                const float a41 = (float)(44.0/45.0), a42 = (float)(-56.0/15.0),
                            a43 = (float)(32.0/9.0);
                v0 = fmaf(h, a41*k00 + a42*k10 + a43*k20, y0);
                v1 = fmaf(h, a41*k01 + a42*k11 + a43*k21, y1);
                v2 = fmaf(h, a41*k02 + a42*k12 + a43*k22, y2);
                tt = t0 + 0.8f*h;
            } break;
            case 4: {
                const float a51 = (float)(19372.0/6561.0), a52 = (float)(-25360.0/2187.0),
                            a53 = (float)(64448.0/6561.0), a54 = (float)(-212.0/729.0);
                v0 = fmaf(h, a51*k00 + a52*k10 + a53*k20 + a54*k30, y0);
                v1 = fmaf(h, a51*k01 + a52*k11 + a53*k21 + a54*k31, y1);
                v2 = fmaf(h, a51*k02 + a52*k12 + a53*k22 + a54*k32, y2);
                tt = t0 + (float)(8.0/9.0)*h;
            } break;
            default: {
                const float a61 = (float)(9017.0/3168.0), a62 = (float)(-355.0/33.0),
                            a63 = (float)(46732.0/5247.0), a64 = (float)(49.0/176.0),
                            a65 = (float)(-5103.0/18656.0);
                v0 = fmaf(h, a61*k00 + a62*k10 + a63*k20 + a64*k30 + a65*k40, y0);
                v1 = fmaf(h, a61*k01 + a62*k11 + a63*k21 + a64*k31 + a65*k41, y1);
                v2 = fmaf(h, a61*k02 + a62*k12 + a63*k22 + a64*k32 + a65*k42, y2);
                tt = t0 + h;
            } break;
            }

            // ---- fused layer1+layer2: zz[j] = b2[j] + sum_i tanh(S_i + ...) * W2[i][j]
#define ZDECL(j) float zz_##j = b2v[j];
            R64(ZDECL)
#undef ZDECL
#pragma unroll 2
            for (int i = 0; i < HIDN; ++i) {
                float z = S_lds[i][tid];                 // ds_read_b32, conflict-free
                z = fmaf(v0, W1[0*HIDN + i], z);
                z = fmaf(v1, W1[1*HIDN + i], z);
                z = fmaf(v2, W1[2*HIDN + i], z);
                z = fmaf(tt, W1[64*HIDN + i], z);
                const float ai = fast_tanh(z);
                const float* __restrict__ w2r = W2 + i * HIDN;  // uniform -> s_load
#define ZFMA(j) zz_##j = fmaf(ai, w2r[j], zz_##j);
                R64(ZFMA)
#undef ZFMA
            }

            // ---- layer 3: 64 -> 3, fused with tanh(zz) ----
            float o0 = b3v[0], o1 = b3v[1], o2 = b3v[2];
#define ZOUT(j) { const float t2 = fast_tanh(zz_##j);          \
                  o0 = fmaf(t2, W3[(j)*3 + 0], o0);            \
                  o1 = fmaf(t2, W3[(j)*3 + 1], o1);            \
                  o2 = fmaf(t2, W3[(j)*3 + 2], o2); }
            R64(ZOUT)
#undef ZOUT
            const float r0 = fast_tanh(o0) * scale;
            const float r1 = fast_tanh(o1) * scale;
            const float r2 = fast_tanh(o2) * scale;

            switch (st) {
            case 0: k00=r0; k01=r1; k02=r2; break;
            case 1: k10=r0; k11=r1; k12=r2; break;
            case 2: k20=r0; k21=r1; k22=r2; break;
            case 3: k30=r0; k31=r1; k32=r2; break;
            case 4: k40=r0; k41=r1; k42=r2; break;
            default: {   // st==5: r is k6 — final 5th-order combine
                const float c1 = (float)(35.0/384.0),  c3 = (float)(500.0/1113.0),
                            c4 = (float)(125.0/192.0), c5 = (float)(-2187.0/6784.0),
                            c6 = (float)(11.0/84.0);
                y0 = fmaf(h, c1*k00 + c3*k20 + c4*k30 + c5*k40 + c6*r0, y0);
                y1 = fmaf(h, c1*k01 + c3*k21 + c4*k31 + c5*k41 + c6*r1, y1);
                y2 = fmaf(h, c1*k02 + c3*k22 + c4*k32 + c5*k42 + c6*r2, y2);
            } break;
            }
        }
    }

    out[b*3 + 0] = y0;
    out[b*3 + 1] = y1;
    out[b*3 + 2] = y2;
}

extern "C" void kernel_launch(void* const* d_in, const int* in_sizes, int n_in,
                              void* d_out, int out_size, void* d_ws, size_t ws_size,
                              hipStream_t stream) {
    const float* pad0 = (const float*)d_in[0];
    const float* sens = (const float*)d_in[1];
    const float* W1   = (const float*)d_in[2];
    const float* b1v  = (const float*)d_in[3];
    const float* W2   = (const float*)d_in[4];
    const float* b2v  = (const float*)d_in[5];
    const float* W3   = (const float*)d_in[6];
    const float* b3v  = (const float*)d_in[7];
    const float* sc   = (const float*)d_in[8];
    float* out = (float*)d_out;

    dim3 grid(BATCH / TPB), block(TPB);
    hipLaunchKernelGGL(node_kernel, grid, block, 0, stream,
                       pad0, sens, W1, b1v, W2, b2v, W3, b3v, sc, out);
}

// Round 4
// 610.006 us; speedup vs baseline: 2.1947x; 2.1947x over previous
//
#include <hip/hip_runtime.h>

typedef __bf16 v8bf __attribute__((ext_vector_type(8)));
typedef float  v4f  __attribute__((ext_vector_type(4)));
typedef int    v4i  __attribute__((ext_vector_type(4)));
union FR { v4i i4; v8bf bf; };

static constexpr int BATCH = 131072;
static constexpr int SENSN = 61;
static constexpr int NSTEP = 10;
static constexpr int TPB   = 256;
static constexpr int ROWP  = 72;   // ushorts per staged row: 64 data + 8 pad = 144 B (conflict-free, 16B-aligned)

#define R64(M) \
  M(0) M(1) M(2) M(3) M(4) M(5) M(6) M(7) \
  M(8) M(9) M(10) M(11) M(12) M(13) M(14) M(15) \
  M(16) M(17) M(18) M(19) M(20) M(21) M(22) M(23) \
  M(24) M(25) M(26) M(27) M(28) M(29) M(30) M(31) \
  M(32) M(33) M(34) M(35) M(36) M(37) M(38) M(39) \
  M(40) M(41) M(42) M(43) M(44) M(45) M(46) M(47) \
  M(48) M(49) M(50) M(51) M(52) M(53) M(54) M(55) \
  M(56) M(57) M(58) M(59) M(60) M(61) M(62) M(63)

#define R32P(M) \
  M(0,1) M(2,3) M(4,5) M(6,7) M(8,9) M(10,11) M(12,13) M(14,15) \
  M(16,17) M(18,19) M(20,21) M(22,23) M(24,25) M(26,27) M(28,29) M(30,31) \
  M(32,33) M(34,35) M(36,37) M(38,39) M(40,41) M(42,43) M(44,45) M(46,47) \
  M(48,49) M(50,51) M(52,53) M(54,55) M(56,57) M(58,59) M(60,61) M(62,63)

// pack two f32 -> dword of 2 bf16 (truncation round): low16 = bf16(lo), hi16 = bf16(hi)
__device__ __forceinline__ unsigned pk(float hi, float lo) {
    return __builtin_amdgcn_perm(__float_as_uint(hi), __float_as_uint(lo), 0x07060302u);
}

__global__ void __launch_bounds__(TPB, 2)
node_kernel(const float* __restrict__ pad0,
            const float* __restrict__ sens,
            const float* __restrict__ W1,
            const float* __restrict__ b1v,
            const float* __restrict__ W2,
            const float* __restrict__ b2v,
            const float* __restrict__ W3,
            const float* __restrict__ b3v,
            const float* __restrict__ scale_p,
            float* __restrict__ out)
{
    // per-wave staging tile: [64 rows][72 ushorts]; also reused as f32 o-buffer
    __shared__ ushort abuf[4 * 64 * ROWP];

    const int tid  = threadIdx.x;
    const int wv   = tid >> 6;
    const int lane = tid & 63;
    const int lo   = lane & 15;
    const int hh   = lane >> 4;
    const int b    = blockIdx.x * TPB + tid;

    ushort* __restrict__ aw = abuf + wv * 64 * ROWP;
    float*  __restrict__ ob = reinterpret_cast<float*>(aw);   // 64 rows x 4 f32 = 1 KB

    const float L     = 2.885390081777927f;  // 2*log2(e): exp(2x) = exp2(L*x)
    const float scale = scale_p[0];
    const float m2L   = -2.0f * L;
    const float m2s   = -2.0f * scale;
    const float h     = 0.1f;

    // ---- one-time: W2 B-fragments (B[k][col]: lane holds col=lo+16tn, k=hh*8+i+32kc) ----
    FR b2f[4][2];
#pragma unroll
    for (int tn = 0; tn < 4; ++tn)
#pragma unroll
        for (int kc = 0; kc < 2; ++kc) {
            float w[8];
#pragma unroll
            for (int i = 0; i < 8; ++i)
                w[i] = W2[(hh*8 + i + 32*kc)*64 + lo + 16*tn];
            b2f[tn][kc].i4 = (v4i){ (int)pk(w[1],w[0]), (int)pk(w[3],w[2]),
                                    (int)pk(w[5],w[4]), (int)pk(w[7],w[6]) };
        }
    // W3 B-fragments (N=3 padded to 16; cols >=3 zero)
    FR w3f[2];
#pragma unroll
    for (int kc = 0; kc < 2; ++kc) {
        float w[8];
#pragma unroll
        for (int i = 0; i < 8; ++i)
            w[i] = (lo < 3) ? W3[(hh*8 + i + 32*kc)*3 + lo] : 0.0f;
        w3f[kc].i4 = (v4i){ (int)pk(w[1],w[0]), (int)pk(w[3],w[2]),
                            (int)pk(w[5],w[4]), (int)pk(w[7],w[6]) };
    }
    float b2L[4];
#pragma unroll
    for (int tn = 0; tn < 4; ++tn) b2L[tn] = L * b2v[lo + 16*tn];
    const float b3L = (lo < 3) ? L * b3v[lo] : 0.0f;

    const float* __restrict__ w1r0 = W1;          // row 0 (y0)
    const float* __restrict__ w1r1 = W1 + 64;     // row 1 (y1)
    const float* __restrict__ w1r2 = W1 + 128;    // row 2 (y2)
    const float* __restrict__ w1rt = W1 + 4096;   // row 64 (t)

    // ---- one-time: S'[i] = L*(b1[i] + sensory[b,:] @ W1[3:64,i])  (named scalars -> VGPRs) ----
#define SDECL(j) float s_##j = b1v[j];
    R64(SDECL)
#undef SDECL
    {
        const float* __restrict__ srow = sens + (long)b * SENSN;
#pragma unroll 1
        for (int s = 0; s < SENSN; ++s) {
            const float xv = srow[s];
            const float* __restrict__ w = W1 + (3 + s) * 64;
#define SFMA(j) s_##j = fmaf(xv, w[j], s_##j);
            R64(SFMA)
#undef SFMA
        }
    }
#define SSC(j) s_##j *= L;
    R64(SSC)
#undef SSC

    float y0 = pad0[b*3 + 0];
    float y1 = pad0[b*3 + 1];
    float y2 = pad0[b*3 + 2];

    float k00=0,k01=0,k02=0, k10=0,k11=0,k12=0, k20=0,k21=0,k22=0,
          k30=0,k31=0,k32=0, k40=0,k41=0,k42=0;

#pragma unroll 1
    for (int step = 0; step < NSTEP; ++step) {
        const float t0 = (float)step * h;
#pragma unroll 1
        for (int st = 0; st < 6; ++st) {
            // ---- phase A: dopri5 stage combine (wave-uniform switch) ----
            float tt = t0, v0 = y0, v1 = y1, v2 = y2;
            switch (st) {
            case 0: break;
            case 1: {
                const float a21 = 0.2f;
                v0 = fmaf(h, a21*k00, y0); v1 = fmaf(h, a21*k01, y1); v2 = fmaf(h, a21*k02, y2);
                tt = t0 + 0.2f*h;
            } break;
            case 2: {
                const float a31 = 3.f/40.f, a32 = 9.f/40.f;
                v0 = fmaf(h, a31*k00 + a32*k10, y0);
                v1 = fmaf(h, a31*k01 + a32*k11, y1);
                v2 = fmaf(h, a31*k02 + a32*k12, y2);
                tt = t0 + 0.3f*h;
            } break;
            case 3: {
                const float a41 = 44.f/45.f, a42 = -56.f/15.f, a43 = 32.f/9.f;
                v0 = fmaf(h, a41*k00 + a42*k10 + a43*k20, y0);
                v1 = fmaf(h, a41*k01 + a42*k11 + a43*k21, y1);
                v2 = fmaf(h, a41*k02 + a42*k12 + a43*k22, y2);
                tt = t0 + 0.8f*h;
            } break;
            case 4: {
                const float a51 = 19372.f/6561.f, a52 = -25360.f/2187.f,
                            a53 = 64448.f/6561.f, a54 = -212.f/729.f;
                v0 = fmaf(h, a51*k00 + a52*k10 + a53*k20 + a54*k30, y0);
                v1 = fmaf(h, a51*k01 + a52*k11 + a53*k21 + a54*k31, y1);
                v2 = fmaf(h, a51*k02 + a52*k12 + a53*k22 + a54*k32, y2);
                tt = t0 + (8.f/9.f)*h;
            } break;
            default: {
                const float a61 = 9017.f/3168.f, a62 = -355.f/33.f,
                            a63 = 46732.f/5247.f, a64 = 49.f/176.f, a65 = -5103.f/18656.f;
                v0 = fmaf(h, a61*k00 + a62*k10 + a63*k20 + a64*k30 + a65*k40, y0);
                v1 = fmaf(h, a61*k01 + a62*k11 + a63*k21 + a64*k31 + a65*k41, y1);
                v2 = fmaf(h, a61*k02 + a62*k12 + a63*k22 + a64*k32 + a65*k42, y2);
                tt = t0 + h;
            } break;
            }
            const float v0p = L*v0, v1p = L*v1, v2p = L*v2, ttp = L*tt;

            // ---- phase B: layer1 (rank-4 on S') + tanh + pack pairs, stage row to LDS ----
            unsigned pw[32];
#define L1P(i0,i1) { \
    float za = s_##i0; \
    za = fmaf(v0p, w1r0[i0], za); za = fmaf(v1p, w1r1[i0], za); \
    za = fmaf(v2p, w1r2[i0], za); za = fmaf(ttp, w1rt[i0], za); \
    float ea = exp2f(za); float ra = __builtin_amdgcn_rcpf(ea + 1.0f); \
    float ta = fmaf(m2L, ra, L); \
    float zb = s_##i1; \
    zb = fmaf(v0p, w1r0[i1], zb); zb = fmaf(v1p, w1r1[i1], zb); \
    zb = fmaf(v2p, w1r2[i1], zb); zb = fmaf(ttp, w1rt[i1], zb); \
    float eb = exp2f(zb); float rb = __builtin_amdgcn_rcpf(eb + 1.0f); \
    float tb = fmaf(m2L, rb, L); \
    pw[(i0)/2] = pk(tb, ta); }
            R32P(L1P)
#undef L1P
            {
                v4i* __restrict__ dst = (v4i*)&aw[lane * ROWP];
#pragma unroll
                for (int w8 = 0; w8 < 8; ++w8)
                    dst[w8] = (v4i){ (int)pw[4*w8+0], (int)pw[4*w8+1],
                                     (int)pw[4*w8+2], (int)pw[4*w8+3] };
            }
            asm volatile("" ::: "memory");

            // ---- phase C: layer2 = 32 MFMA (A from LDS, B = W2 frags) ----
            const v4f z4 = {0.f, 0.f, 0.f, 0.f};
            v4f acc[4][4];
#pragma unroll
            for (int tm = 0; tm < 4; ++tm) {
                FR a0, a1;
                a0.i4 = *(const v4i*)&aw[(lo + 16*tm)*ROWP + hh*8];
                a1.i4 = *(const v4i*)&aw[(lo + 16*tm)*ROWP + hh*8 + 32];
#pragma unroll
                for (int tn = 0; tn < 4; ++tn) {
                    v4f t = __builtin_amdgcn_mfma_f32_16x16x32_bf16(a0.bf, b2f[tn][0].bf, z4, 0, 0, 0);
                    acc[tm][tn] = __builtin_amdgcn_mfma_f32_16x16x32_bf16(a1.bf, b2f[tn][1].bf, t, 0, 0, 0);
                }
            }

            // ---- phase D: tanh(zz) in C-layout, scatter bf16 back to LDS [row][col] ----
#pragma unroll
            for (int tm = 0; tm < 4; ++tm)
#pragma unroll
                for (int tn = 0; tn < 4; ++tn)
#pragma unroll
                    for (int q = 0; q < 4; ++q) {
                        float zp = acc[tm][tn][q] + b2L[tn];
                        float e  = exp2f(zp);
                        float rr = __builtin_amdgcn_rcpf(e + 1.0f);
                        float t2 = fmaf(m2L, rr, L);
                        aw[(16*tm + 4*hh + q)*ROWP + lo + 16*tn] =
                            (ushort)(__float_as_uint(t2) >> 16);
                    }
            asm volatile("" ::: "memory");

            // ---- phase E: layer3 = 8 MFMA (N=3 padded) ----
            v4f c3[4];
#pragma unroll
            for (int tm = 0; tm < 4; ++tm) {
                FR x0, x1;
                x0.i4 = *(const v4i*)&aw[(lo + 16*tm)*ROWP + hh*8];
                x1.i4 = *(const v4i*)&aw[(lo + 16*tm)*ROWP + hh*8 + 32];
                v4f t = __builtin_amdgcn_mfma_f32_16x16x32_bf16(x0.bf, w3f[0].bf, z4, 0, 0, 0);
                c3[tm] = __builtin_amdgcn_mfma_f32_16x16x32_bf16(x1.bf, w3f[1].bf, t, 0, 0, 0);
            }

            // ---- phase F: C3 -> per-row o-buffer (cols 0..2 valid) ----
            if (lo < 3) {
#pragma unroll
                for (int tm = 0; tm < 4; ++tm)
#pragma unroll
                    for (int q = 0; q < 4; ++q)
                        ob[(16*tm + 4*hh + q)*4 + lo] = c3[tm][q] + b3L;
            }
            asm volatile("" ::: "memory");

            // ---- phase G: back to lane=row, final tanh*scale, RK bookkeeping ----
            const float4 ov = *(const float4*)&ob[lane * 4];
            const float r0 = fmaf(m2s, __builtin_amdgcn_rcpf(exp2f(ov.x) + 1.0f), scale);
            const float r1 = fmaf(m2s, __builtin_amdgcn_rcpf(exp2f(ov.y) + 1.0f), scale);
            const float r2 = fmaf(m2s, __builtin_amdgcn_rcpf(exp2f(ov.z) + 1.0f), scale);
            asm volatile("" ::: "memory");

            switch (st) {
            case 0: k00=r0; k01=r1; k02=r2; break;
            case 1: k10=r0; k11=r1; k12=r2; break;
            case 2: k20=r0; k21=r1; k22=r2; break;
            case 3: k30=r0; k31=r1; k32=r2; break;
            case 4: k40=r0; k41=r1; k42=r2; break;
            default: {
                const float c1 = 35.f/384.f,  c3c = 500.f/1113.f,
                            c4 = 125.f/192.f, c5 = -2187.f/6784.f, c6 = 11.f/84.f;
                y0 = fmaf(h, c1*k00 + c3c*k20 + c4*k30 + c5*k40 + c6*r0, y0);
                y1 = fmaf(h, c1*k01 + c3c*k21 + c4*k31 + c5*k41 + c6*r1, y1);
                y2 = fmaf(h, c1*k02 + c3c*k22 + c4*k32 + c5*k42 + c6*r2, y2);
            } break;
            }
        }
    }

    out[b*3 + 0] = y0;
    out[b*3 + 1] = y1;
    out[b*3 + 2] = y2;
}

extern "C" void kernel_launch(void* const* d_in, const int* in_sizes, int n_in,
                              void* d_out, int out_size, void* d_ws, size_t ws_size,
                              hipStream_t stream) {
    const float* pad0 = (const float*)d_in[0];
    const float* sens = (const float*)d_in[1];
    const float* W1   = (const float*)d_in[2];
    const float* b1v  = (const float*)d_in[3];
    const float* W2   = (const float*)d_in[4];
    const float* b2v  = (const float*)d_in[5];
    const float* W3   = (const float*)d_in[6];
    const float* b3v  = (const float*)d_in[7];
    const float* sc   = (const float*)d_in[8];
    float* outp = (float*)d_out;

    dim3 grid(BATCH / TPB), block(TPB);
    hipLaunchKernelGGL(node_kernel, grid, block, 0, stream,
                       pad0, sens, W1, b1v, W2, b2v, W3, b3v, sc, outp);
}

// Round 6
// 574.230 us; speedup vs baseline: 2.3315x; 1.0623x over previous
//
#include <hip/hip_runtime.h>

typedef __bf16 v8bf __attribute__((ext_vector_type(8)));
typedef float  v4f  __attribute__((ext_vector_type(4)));
typedef int    v4i  __attribute__((ext_vector_type(4)));
union FR { v4i i4; v8bf bf; };

static constexpr int BATCH = 131072;
static constexpr int SENSN = 61;
static constexpr int NSTEP = 10;
static constexpr int TPB   = 256;
static constexpr int ROWP  = 72;   // ushorts per staged row: 64 data + 8 pad = 144 B

#if __has_builtin(__builtin_amdgcn_exp2f)
#define EXP2(x) __builtin_amdgcn_exp2f(x)
#else
#define EXP2(x) exp2f(x)
#endif
#define RCP(x) __builtin_amdgcn_rcpf(x)

#define R64(M) \
  M(0) M(1) M(2) M(3) M(4) M(5) M(6) M(7) \
  M(8) M(9) M(10) M(11) M(12) M(13) M(14) M(15) \
  M(16) M(17) M(18) M(19) M(20) M(21) M(22) M(23) \
  M(24) M(25) M(26) M(27) M(28) M(29) M(30) M(31) \
  M(32) M(33) M(34) M(35) M(36) M(37) M(38) M(39) \
  M(40) M(41) M(42) M(43) M(44) M(45) M(46) M(47) \
  M(48) M(49) M(50) M(51) M(52) M(53) M(54) M(55) \
  M(56) M(57) M(58) M(59) M(60) M(61) M(62) M(63)

#define R32P(M) \
  M(0,1) M(2,3) M(4,5) M(6,7) M(8,9) M(10,11) M(12,13) M(14,15) \
  M(16,17) M(18,19) M(20,21) M(22,23) M(24,25) M(26,27) M(28,29) M(30,31) \
  M(32,33) M(34,35) M(36,37) M(38,39) M(40,41) M(42,43) M(44,45) M(46,47) \
  M(48,49) M(50,51) M(52,53) M(54,55) M(56,57) M(58,59) M(60,61) M(62,63)

// pack two f32 -> dword of 2 bf16 (truncation): low16 = bf16(lo), hi16 = bf16(hi)
__device__ __forceinline__ unsigned pk(float hi, float lo) {
    return __builtin_amdgcn_perm(__float_as_uint(hi), __float_as_uint(lo), 0x07060302u);
}

__global__ void __launch_bounds__(TPB, 2)
node_kernel(const float* __restrict__ pad0,
            const float* __restrict__ sens,
            const float* __restrict__ W1,
            const float* __restrict__ b1v,
            const float* __restrict__ W2,
            const float* __restrict__ b2v,
            const float* __restrict__ W3,
            const float* __restrict__ b3v,
            const float* __restrict__ scale_p,
            float* __restrict__ out)
{
    // per-wave staging tile [64][ROWP] ushort; first 1 KB reused as f32 o-buffer
    __shared__ ushort abuf[4 * 64 * ROWP];

    const int tid  = threadIdx.x;
    const int wv   = tid >> 6;
    const int lane = tid & 63;
    const int lo   = lane & 15;
    const int hh   = lane >> 4;
    const int b    = blockIdx.x * TPB + tid;

    ushort* __restrict__ aw = abuf + wv * 64 * ROWP;
    float*  __restrict__ ob = reinterpret_cast<float*>(aw);   // 64 rows x 4 f32

    const float L     = 2.885390081777927f;  // 2*log2(e): exp(2x) = exp2(L*x)
    const float scale = scale_p[0];
    const float m2L   = -2.0f * L;
    const float m2s   = -2.0f * scale;
    const float h     = 0.1f;

    // ---- one-time: W2 fragments; used as MFMA *A*-operand => computes W2^T @ a^T ----
    // lane holds W2[hh*8+i+32*kc][lo+16*jb]  (A-frag: row=lo (j-block), k=hh*8+i)
    FR b2f[4][2];
#pragma unroll
    for (int jb = 0; jb < 4; ++jb)
#pragma unroll
        for (int kc = 0; kc < 2; ++kc) {
            float w[8];
#pragma unroll
            for (int i = 0; i < 8; ++i)
                w[i] = W2[(hh*8 + i + 32*kc)*64 + lo + 16*jb];
            b2f[jb][kc].i4 = (v4i){ (int)pk(w[1],w[0]), (int)pk(w[3],w[2]),
                                    (int)pk(w[5],w[4]), (int)pk(w[7],w[6]) };
        }
    // layer-3 weights per lane: W3L[jb][q][n] = W3[16jb+4hh+q][n]
    float W3L[4][4][3];
#pragma unroll
    for (int jb = 0; jb < 4; ++jb)
#pragma unroll
        for (int q = 0; q < 4; ++q)
#pragma unroll
            for (int n = 0; n < 3; ++n)
                W3L[jb][q][n] = W3[(16*jb + 4*hh + q)*3 + n];
    // L-prescaled layer-2 bias per lane (j = 16jb+4hh+q)
    float b2c[4][4];
#pragma unroll
    for (int jb = 0; jb < 4; ++jb)
#pragma unroll
        for (int q = 0; q < 4; ++q)
            b2c[jb][q] = L * b2v[16*jb + 4*hh + q];
    const float b3L0 = L * b3v[0], b3L1 = L * b3v[1], b3L2 = L * b3v[2];

    const float* __restrict__ w1r0 = W1;          // row 0 (y0)
    const float* __restrict__ w1r1 = W1 + 64;     // row 1 (y1)
    const float* __restrict__ w1r2 = W1 + 128;    // row 2 (y2)
    const float* __restrict__ w1rt = W1 + 4096;   // row 64 (t)

    // ---- one-time: S'[i] = L*(b1[i] + sensory[b,:] @ W1[3:64,i]) in named VGPRs ----
#define SDECL(j) float s_##j = b1v[j];
    R64(SDECL)
#undef SDECL
    {
        const float* __restrict__ srow = sens + (long)b * SENSN;
#pragma unroll 1
        for (int s = 0; s < SENSN; ++s) {
            const float xv = srow[s];
            const float* __restrict__ w = W1 + (3 + s) * 64;
#define SFMA(j) s_##j = fmaf(xv, w[j], s_##j);
            R64(SFMA)
#undef SFMA
        }
    }
#define SSC(j) s_##j *= L;
    R64(SSC)
#undef SSC

    float y0 = pad0[b*3 + 0];
    float y1 = pad0[b*3 + 1];
    float y2 = pad0[b*3 + 2];

    float k00=0,k01=0,k02=0, k10=0,k11=0,k12=0, k20=0,k21=0,k22=0,
          k30=0,k31=0,k32=0, k40=0,k41=0,k42=0;

#pragma unroll 1
    for (int step = 0; step < NSTEP; ++step) {
        const float t0 = (float)step * h;
#pragma unroll 1
        for (int st = 0; st < 6; ++st) {
            // ---- phase A: dopri5 stage combine (wave-uniform switch) ----
            float tt = t0, v0 = y0, v1 = y1, v2 = y2;
            switch (st) {
            case 0: break;
            case 1: {
                const float a21 = 0.2f;
                v0 = fmaf(h, a21*k00, y0); v1 = fmaf(h, a21*k01, y1); v2 = fmaf(h, a21*k02, y2);
                tt = t0 + 0.2f*h;
            } break;
            case 2: {
                const float a31 = 3.f/40.f, a32 = 9.f/40.f;
                v0 = fmaf(h, a31*k00 + a32*k10, y0);
                v1 = fmaf(h, a31*k01 + a32*k11, y1);
                v2 = fmaf(h, a31*k02 + a32*k12, y2);
                tt = t0 + 0.3f*h;
            } break;
            case 3: {
                const float a41 = 44.f/45.f, a42 = -56.f/15.f, a43 = 32.f/9.f;
                v0 = fmaf(h, a41*k00 + a42*k10 + a43*k20, y0);
                v1 = fmaf(h, a41*k01 + a42*k11 + a43*k21, y1);
                v2 = fmaf(h, a41*k02 + a42*k12 + a43*k22, y2);
                tt = t0 + 0.8f*h;
            } break;
            case 4: {
                const float a51 = 19372.f/6561.f, a52 = -25360.f/2187.f,
                            a53 = 64448.f/6561.f, a54 = -212.f/729.f;
                v0 = fmaf(h, a51*k00 + a52*k10 + a53*k20 + a54*k30, y0);
                v1 = fmaf(h, a51*k01 + a52*k11 + a53*k21 + a54*k31, y1);
                v2 = fmaf(h, a51*k02 + a52*k12 + a53*k22 + a54*k32, y2);
                tt = t0 + (8.f/9.f)*h;
            } break;
            default: {
                const float a61 = 9017.f/3168.f, a62 = -355.f/33.f,
                            a63 = 46732.f/5247.f, a64 = 49.f/176.f, a65 = -5103.f/18656.f;
                v0 = fmaf(h, a61*k00 + a62*k10 + a63*k20 + a64*k30 + a65*k40, y0);
                v1 = fmaf(h, a61*k01 + a62*k11 + a63*k21 + a64*k31 + a65*k41, y1);
                v2 = fmaf(h, a61*k02 + a62*k12 + a63*k22 + a64*k32 + a65*k42, y2);
                tt = t0 + h;
            } break;
            }
            const float v0p = L*v0, v1p = L*v1, v2p = L*v2, ttp = L*tt;

            // ---- phase B: layer1 rank-4 + tanh (raw v_exp), stage row as bf16 ----
            unsigned pw[32];
#define L1P(i0,i1) { \
    float za = s_##i0; \
    za = fmaf(v0p, w1r0[i0], za); za = fmaf(v1p, w1r1[i0], za); \
    za = fmaf(v2p, w1r2[i0], za); za = fmaf(ttp, w1rt[i0], za); \
    float ta = fmaf(m2L, RCP(EXP2(za) + 1.0f), L); \
    float zb = s_##i1; \
    zb = fmaf(v0p, w1r0[i1], zb); zb = fmaf(v1p, w1r1[i1], zb); \
    zb = fmaf(v2p, w1r2[i1], zb); zb = fmaf(ttp, w1rt[i1], zb); \
    float tb = fmaf(m2L, RCP(EXP2(zb) + 1.0f), L); \
    pw[(i0)/2] = pk(tb, ta); }
            R32P(L1P)
#undef L1P
            {
                v4i* __restrict__ dst = (v4i*)&aw[lane * ROWP];
#pragma unroll
                for (int w8 = 0; w8 < 8; ++w8)
                    dst[w8] = (v4i){ (int)pw[4*w8+0], (int)pw[4*w8+1],
                                     (int)pw[4*w8+2], (int)pw[4*w8+3] };
            }
            asm volatile("" ::: "memory");

            // ---- phase C: layer2 swapped: acc[jb][nb] = zzT[j][batch] ----
            const v4f z4 = {0.f, 0.f, 0.f, 0.f};
            v4f acc[4][4];
#pragma unroll
            for (int nb = 0; nb < 4; ++nb) {
                FR a0, a1;
                a0.i4 = *(const v4i*)&aw[(lo + 16*nb)*ROWP + hh*8];
                a1.i4 = *(const v4i*)&aw[(lo + 16*nb)*ROWP + hh*8 + 32];
#pragma unroll
                for (int jb = 0; jb < 4; ++jb) {
                    v4f t = __builtin_amdgcn_mfma_f32_16x16x32_bf16(b2f[jb][0].bf, a0.bf, z4, 0, 0, 0);
                    acc[jb][nb] = __builtin_amdgcn_mfma_f32_16x16x32_bf16(b2f[jb][1].bf, a1.bf, t, 0, 0, 0);
                }
            }

            // ---- phase D: tanh in-register (j lane-local; no scatter, stays f32) ----
#pragma unroll
            for (int jb = 0; jb < 4; ++jb)
#pragma unroll
                for (int nb = 0; nb < 4; ++nb)
#pragma unroll
                    for (int q = 0; q < 4; ++q) {
                        float z = acc[jb][nb][q] + b2c[jb][q];
                        acc[jb][nb][q] = fmaf(m2L, RCP(EXP2(z) + 1.0f), L);  // L*tanh
                    }

            // ---- phase E: layer3 on VALU: per-lane partial over 16 local j's ----
            float p[4][3];
#pragma unroll
            for (int nb = 0; nb < 4; ++nb)
#pragma unroll
                for (int n = 0; n < 3; ++n) {
                    float s = 0.0f;
#pragma unroll
                    for (int jb = 0; jb < 4; ++jb)
#pragma unroll
                        for (int q = 0; q < 4; ++q)
                            s = fmaf(acc[jb][nb][q], W3L[jb][q][n], s);
                    p[nb][n] = s;
                }
            // butterfly over the 4 hh-lanes (same lo): xor 16, xor 32
#pragma unroll
            for (int nb = 0; nb < 4; ++nb)
#pragma unroll
                for (int n = 0; n < 3; ++n) {
                    float v = p[nb][n];
                    v += __shfl_xor(v, 16, 64);
                    v += __shfl_xor(v, 32, 64);
                    p[nb][n] = v;
                }

            // ---- phase F: hh==0 lanes write L*o to o-buffer rows lo+16nb ----
            if (hh == 0) {
#pragma unroll
                for (int nb = 0; nb < 4; ++nb)
#pragma unroll
                    for (int n = 0; n < 3; ++n)
                        ob[(lo + 16*nb)*4 + n] = p[nb][n];
            }
            asm volatile("" ::: "memory");

            // ---- phase G: lane=row readback, final tanh*scale, RK bookkeeping ----
            const float4 ov = *(const float4*)&ob[lane * 4];
            const float r0 = fmaf(m2s, RCP(EXP2(ov.x + b3L0) + 1.0f), scale);
            const float r1 = fmaf(m2s, RCP(EXP2(ov.y + b3L1) + 1.0f), scale);
            const float r2 = fmaf(m2s, RCP(EXP2(ov.z + b3L2) + 1.0f), scale);
            asm volatile("" ::: "memory");

            switch (st) {
            case 0: k00=r0; k01=r1; k02=r2; break;
            case 1: k10=r0; k11=r1; k12=r2; break;
            case 2: k20=r0; k21=r1; k22=r2; break;
            case 3: k30=r0; k31=r1; k32=r2; break;
            case 4: k40=r0; k41=r1; k42=r2; break;
            default: {
                const float c1 = 35.f/384.f,  c3c = 500.f/1113.f,
                            c4 = 125.f/192.f, c5 = -2187.f/6784.f, c6 = 11.f/84.f;
                y0 = fmaf(h, c1*k00 + c3c*k20 + c4*k30 + c5*k40 + c6*r0, y0);
                y1 = fmaf(h, c1*k01 + c3c*k21 + c4*k31 + c5*k41 + c6*r1, y1);
                y2 = fmaf(h, c1*k02 + c3c*k22 + c4*k32 + c5*k42 + c6*r2, y2);
            } break;
            }
        }
    }

    out[b*3 + 0] = y0;
    out[b*3 + 1] = y1;
    out[b*3 + 2] = y2;
}

extern "C" void kernel_launch(void* const* d_in, const int* in_sizes, int n_in,
                              void* d_out, int out_size, void* d_ws, size_t ws_size,
                              hipStream_t stream) {
    const float* pad0 = (const float*)d_in[0];
    const float* sens = (const float*)d_in[1];
    const float* W1   = (const float*)d_in[2];
    const float* b1v  = (const float*)d_in[3];
    const float* W2   = (const float*)d_in[4];
    const float* b2v  = (const float*)d_in[5];
    const float* W3   = (const float*)d_in[6];
    const float* b3v  = (const float*)d_in[7];
    const float* sc   = (const float*)d_in[8];
    float* outp = (float*)d_out;

    dim3 grid(BATCH / TPB), block(TPB);
    hipLaunchKernelGGL(node_kernel, grid, block, 0, stream,
                       pad0, sens, W1, b1v, W2, b2v, W3, b3v, sc, outp);
}

// Round 8
// 501.589 us; speedup vs baseline: 2.6691x; 1.1448x over previous
//
#include <hip/hip_runtime.h>

typedef __bf16 v8bf __attribute__((ext_vector_type(8)));
typedef float  v4f  __attribute__((ext_vector_type(4)));
typedef int    v4i  __attribute__((ext_vector_type(4)));
union FR { v4i i4; v8bf bf; };

static constexpr int BATCH = 131072;
static constexpr int SENSN = 61;
static constexpr int NSTEP = 10;
static constexpr int TPB   = 256;
static constexpr int ROWP  = 96;   // ushorts/row: 192 B stride = 48 words = 16 mod 32 banks -> 2-way (free)

#if __has_builtin(__builtin_amdgcn_exp2f)
#define EXP2(x) __builtin_amdgcn_exp2f(x)
#else
#define EXP2(x) exp2f(x)
#endif
#define RCP(x) __builtin_amdgcn_rcpf(x)

#define R64(M) \
  M(0) M(1) M(2) M(3) M(4) M(5) M(6) M(7) \
  M(8) M(9) M(10) M(11) M(12) M(13) M(14) M(15) \
  M(16) M(17) M(18) M(19) M(20) M(21) M(22) M(23) \
  M(24) M(25) M(26) M(27) M(28) M(29) M(30) M(31) \
  M(32) M(33) M(34) M(35) M(36) M(37) M(38) M(39) \
  M(40) M(41) M(42) M(43) M(44) M(45) M(46) M(47) \
  M(48) M(49) M(50) M(51) M(52) M(53) M(54) M(55) \
  M(56) M(57) M(58) M(59) M(60) M(61) M(62) M(63)

#define R32P(M) \
  M(0,1) M(2,3) M(4,5) M(6,7) M(8,9) M(10,11) M(12,13) M(14,15) \
  M(16,17) M(18,19) M(20,21) M(22,23) M(24,25) M(26,27) M(28,29) M(30,31) \
  M(32,33) M(34,35) M(36,37) M(38,39) M(40,41) M(42,43) M(44,45) M(46,47) \
  M(48,49) M(50,51) M(52,53) M(54,55) M(56,57) M(58,59) M(60,61) M(62,63)

// pack two f32 -> dword of 2 bf16 (truncation): low16 = bf16(lo), hi16 = bf16(hi)
__device__ __forceinline__ unsigned pk(float hi, float lo) {
    return __builtin_amdgcn_perm(__float_as_uint(hi), __float_as_uint(lo), 0x07060302u);
}

__global__ void
__attribute__((amdgpu_flat_work_group_size(256, 256), amdgpu_waves_per_eu(2, 2)))
node_kernel(const float* __restrict__ pad0,
            const float* __restrict__ sens,
            const float* __restrict__ W1,
            const float* __restrict__ b1v,
            const float* __restrict__ W2,
            const float* __restrict__ b2v,
            const float* __restrict__ W3,
            const float* __restrict__ b3v,
            const float* __restrict__ scale_p,
            float* __restrict__ out)
{
    // per-wave staging tile [64][ROWP] ushort
    __shared__ ushort abuf[4 * 64 * ROWP];

    const int tid  = threadIdx.x;
    const int wv   = tid >> 6;
    const int lane = tid & 63;
    const int lo   = lane & 15;
    const int hh   = lane >> 4;
    const int hh0  = (lane >> 4) & 1;   // xor-16 bit
    const int hh1  = (lane >> 5) & 1;   // xor-32 bit
    const int b    = blockIdx.x * TPB + tid;

    ushort* __restrict__ aw = abuf + wv * 64 * ROWP;

    const float L     = 2.885390081777927f;  // 2*log2(e): exp(2x) = exp2(L*x)
    const float scale = scale_p[0];
    const float m2L   = -2.0f * L;
    const float m2s   = -2.0f * scale;
    const float h     = 0.1f;

    // ---- one-time: W2 fragments, used as MFMA A-operand (computes zz^T) ----
    // lane holds W2[hh*8+i+32*kc][lo+16*jb]  (A-frag: m=lo -> j, k=hh*8+i)
    FR b2f[4][2];
#pragma unroll
    for (int jb = 0; jb < 4; ++jb)
#pragma unroll
        for (int kc = 0; kc < 2; ++kc) {
            float w[8];
#pragma unroll
            for (int i = 0; i < 8; ++i)
                w[i] = W2[(hh*8 + i + 32*kc)*64 + lo + 16*jb];
            b2f[jb][kc].i4 = (v4i){ (int)pk(w[1],w[0]), (int)pk(w[3],w[2]),
                                    (int)pk(w[5],w[4]), (int)pk(w[7],w[6]) };
        }
    // layer-3 weights per lane: W3L[jb][q][n] = W3[16jb+4hh+q][n]
    float W3L[4][4][3];
#pragma unroll
    for (int jb = 0; jb < 4; ++jb)
#pragma unroll
        for (int q = 0; q < 4; ++q)
#pragma unroll
            for (int n = 0; n < 3; ++n)
                W3L[jb][q][n] = W3[(16*jb + 4*hh + q)*3 + n];
    // L-prescaled layer-2 bias per lane (j = 16jb+4hh+q)
    float b2c[4][4];
#pragma unroll
    for (int jb = 0; jb < 4; ++jb)
#pragma unroll
        for (int q = 0; q < 4; ++q)
            b2c[jb][q] = L * b2v[16*jb + 4*hh + q];
    const float b3L0 = L * b3v[0], b3L1 = L * b3v[1], b3L2 = L * b3v[2];

    const float* __restrict__ w1r0 = W1;          // row 0 (y0)
    const float* __restrict__ w1r1 = W1 + 64;     // row 1 (y1)
    const float* __restrict__ w1r2 = W1 + 128;    // row 2 (y2)
    const float* __restrict__ w1rt = W1 + 4096;   // row 64 (t)

    // ---- one-time: S'[i] = L*(b1[i] + sensory[b,:] @ W1[3:64,i]) in named VGPRs ----
#define SDECL(j) float s_##j = b1v[j];
    R64(SDECL)
#undef SDECL
    {
        const float* __restrict__ srow = sens + (long)b * SENSN;
#pragma unroll 1
        for (int s = 0; s < SENSN; ++s) {
            const float xv = srow[s];
            const float* __restrict__ w = W1 + (3 + s) * 64;
#define SFMA(j) s_##j = fmaf(xv, w[j], s_##j);
            R64(SFMA)
#undef SFMA
        }
    }
#define SSC(j) s_##j *= L;
    R64(SSC)
#undef SSC

    float y0 = pad0[b*3 + 0];
    float y1 = pad0[b*3 + 1];
    float y2 = pad0[b*3 + 2];

    float k00=0,k01=0,k02=0, k10=0,k11=0,k12=0, k20=0,k21=0,k22=0,
          k30=0,k31=0,k32=0, k40=0,k41=0,k42=0;

#pragma unroll 1
    for (int step = 0; step < NSTEP; ++step) {
        const float t0 = (float)step * h;
#pragma unroll 1
        for (int st = 0; st < 6; ++st) {
            // ---- phase A: dopri5 stage combine (wave-uniform switch) ----
            float tt = t0, v0 = y0, v1 = y1, v2 = y2;
            switch (st) {
            case 0: break;
            case 1: {
                const float a21 = 0.2f;
                v0 = fmaf(h, a21*k00, y0); v1 = fmaf(h, a21*k01, y1); v2 = fmaf(h, a21*k02, y2);
                tt = t0 + 0.2f*h;
            } break;
            case 2: {
                const float a31 = 3.f/40.f, a32 = 9.f/40.f;
                v0 = fmaf(h, a31*k00 + a32*k10, y0);
                v1 = fmaf(h, a31*k01 + a32*k11, y1);
                v2 = fmaf(h, a31*k02 + a32*k12, y2);
                tt = t0 + 0.3f*h;
            } break;
            case 3: {
                const float a41 = 44.f/45.f, a42 = -56.f/15.f, a43 = 32.f/9.f;
                v0 = fmaf(h, a41*k00 + a42*k10 + a43*k20, y0);
                v1 = fmaf(h, a41*k01 + a42*k11 + a43*k21, y1);
                v2 = fmaf(h, a41*k02 + a42*k12 + a43*k22, y2);
                tt = t0 + 0.8f*h;
            } break;
            case 4: {
                const float a51 = 19372.f/6561.f, a52 = -25360.f/2187.f,
                            a53 = 64448.f/6561.f, a54 = -212.f/729.f;
                v0 = fmaf(h, a51*k00 + a52*k10 + a53*k20 + a54*k30, y0);
                v1 = fmaf(h, a51*k01 + a52*k11 + a53*k21 + a54*k31, y1);
                v2 = fmaf(h, a51*k02 + a52*k12 + a53*k22 + a54*k32, y2);
                tt = t0 + (8.f/9.f)*h;
            } break;
            default: {
                const float a61 = 9017.f/3168.f, a62 = -355.f/33.f,
                            a63 = 46732.f/5247.f, a64 = 49.f/176.f, a65 = -5103.f/18656.f;
                v0 = fmaf(h, a61*k00 + a62*k10 + a63*k20 + a64*k30 + a65*k40, y0);
                v1 = fmaf(h, a61*k01 + a62*k11 + a63*k21 + a64*k31 + a65*k41, y1);
                v2 = fmaf(h, a61*k02 + a62*k12 + a63*k22 + a64*k32 + a65*k42, y2);
                tt = t0 + h;
            } break;
            }
            const float v0p = L*v0, v1p = L*v1, v2p = L*v2, ttp = L*tt;

            // ---- phase B: layer1 rank-4 + tanh (raw v_exp), stage row as bf16 ----
            unsigned pw[32];
#define L1P(i0,i1) { \
    float za = s_##i0; \
    za = fmaf(v0p, w1r0[i0], za); za = fmaf(v1p, w1r1[i0], za); \
    za = fmaf(v2p, w1r2[i0], za); za = fmaf(ttp, w1rt[i0], za); \
    float ta = fmaf(m2L, RCP(EXP2(za) + 1.0f), L); \
    float zb = s_##i1; \
    zb = fmaf(v0p, w1r0[i1], zb); zb = fmaf(v1p, w1r1[i1], zb); \
    zb = fmaf(v2p, w1r2[i1], zb); zb = fmaf(ttp, w1rt[i1], zb); \
    float tb = fmaf(m2L, RCP(EXP2(zb) + 1.0f), L); \
    pw[(i0)/2] = pk(tb, ta); }
            R32P(L1P)
#undef L1P
            {
                v4i* __restrict__ dst = (v4i*)&aw[lane * ROWP];
#pragma unroll
                for (int w8 = 0; w8 < 8; ++w8)
                    dst[w8] = (v4i){ (int)pw[4*w8+0], (int)pw[4*w8+1],
                                     (int)pw[4*w8+2], (int)pw[4*w8+3] };
            }
            asm volatile("" ::: "memory");

            // ---- phases C/D/E fused, one nb-block at a time (acc live = 16 regs) ----
            const v4f z4 = {0.f, 0.f, 0.f, 0.f};
            float p[4][3];
#pragma unroll
            for (int nb = 0; nb < 4; ++nb) { p[nb][0]=0.f; p[nb][1]=0.f; p[nb][2]=0.f; }
#pragma unroll
            for (int nb = 0; nb < 4; ++nb) {
                FR a0, a1;
                a0.i4 = *(const v4i*)&aw[(lo + 16*nb)*ROWP + hh*8];
                a1.i4 = *(const v4i*)&aw[(lo + 16*nb)*ROWP + hh*8 + 32];
                v4f acc[4];
#pragma unroll
                for (int jb = 0; jb < 4; ++jb) {
                    v4f t = __builtin_amdgcn_mfma_f32_16x16x32_bf16(b2f[jb][0].bf, a0.bf, z4, 0, 0, 0);
                    acc[jb] = __builtin_amdgcn_mfma_f32_16x16x32_bf16(b2f[jb][1].bf, a1.bf, t, 0, 0, 0);
                }
#pragma unroll
                for (int jb = 0; jb < 4; ++jb)
#pragma unroll
                    for (int q = 0; q < 4; ++q) {
                        float z  = acc[jb][q] + b2c[jb][q];
                        float t2 = fmaf(m2L, RCP(EXP2(z) + 1.0f), L);   // L*tanh
                        p[nb][0] = fmaf(t2, W3L[jb][q][0], p[nb][0]);
                        p[nb][1] = fmaf(t2, W3L[jb][q][1], p[nb][1]);
                        p[nb][2] = fmaf(t2, W3L[jb][q][2], p[nb][2]);
                    }
            }
            asm volatile("" ::: "memory");

            // ---- reduce-scatter butterfly: lane d ends with o for batch row d ----
            // stage A (xor 32): keep nb-bit1 == hh1
            float q2[2][3];
#pragma unroll
            for (int j2 = 0; j2 < 2; ++j2)
#pragma unroll
                for (int n = 0; n < 3; ++n) {
                    float keep = hh1 ? p[2+j2][n] : p[j2][n];
                    float send = hh1 ? p[j2][n]   : p[2+j2][n];
                    q2[j2][n] = keep + __shfl_xor(send, 32, 64);
                }
            // stage B (xor 16): keep nb-bit0 == hh0
            float o0, o1, o2;
            {
                float keep0 = hh0 ? q2[1][0] : q2[0][0];
                float send0 = hh0 ? q2[0][0] : q2[1][0];
                o0 = keep0 + __shfl_xor(send0, 16, 64);
                float keep1 = hh0 ? q2[1][1] : q2[0][1];
                float send1 = hh0 ? q2[0][1] : q2[1][1];
                o1 = keep1 + __shfl_xor(send1, 16, 64);
                float keep2 = hh0 ? q2[1][2] : q2[0][2];
                float send2 = hh0 ? q2[0][2] : q2[1][2];
                o2 = keep2 + __shfl_xor(send2, 16, 64);
            }

            // ---- final tanh*scale, RK bookkeeping ----
            const float r0 = fmaf(m2s, RCP(EXP2(o0 + b3L0) + 1.0f), scale);
            const float r1 = fmaf(m2s, RCP(EXP2(o1 + b3L1) + 1.0f), scale);
            const float r2 = fmaf(m2s, RCP(EXP2(o2 + b3L2) + 1.0f), scale);

            switch (st) {
            case 0: k00=r0; k01=r1; k02=r2; break;
            case 1: k10=r0; k11=r1; k12=r2; break;
            case 2: k20=r0; k21=r1; k22=r2; break;
            case 3: k30=r0; k31=r1; k32=r2; break;
            case 4: k40=r0; k41=r1; k42=r2; break;
            default: {
                const float c1 = 35.f/384.f,  c3c = 500.f/1113.f,
                            c4 = 125.f/192.f, c5 = -2187.f/6784.f, c6 = 11.f/84.f;
                y0 = fmaf(h, c1*k00 + c3c*k20 + c4*k30 + c5*k40 + c6*r0, y0);
                y1 = fmaf(h, c1*k01 + c3c*k21 + c4*k31 + c5*k41 + c6*r1, y1);
                y2 = fmaf(h, c1*k02 + c3c*k22 + c4*k32 + c5*k42 + c6*r2, y2);
            } break;
            }
        }
    }

    out[b*3 + 0] = y0;
    out[b*3 + 1] = y1;
    out[b*3 + 2] = y2;
}

extern "C" void kernel_launch(void* const* d_in, const int* in_sizes, int n_in,
                              void* d_out, int out_size, void* d_ws, size_t ws_size,
                              hipStream_t stream) {
    const float* pad0 = (const float*)d_in[0];
    const float* sens = (const float*)d_in[1];
    const float* W1   = (const float*)d_in[2];
    const float* b1v  = (const float*)d_in[3];
    const float* W2   = (const float*)d_in[4];
    const float* b2v  = (const float*)d_in[5];
    const float* W3   = (const float*)d_in[6];
    const float* b3v  = (const float*)d_in[7];
    const float* sc   = (const float*)d_in[8];
    float* outp = (float*)d_out;

    dim3 grid(BATCH / TPB), block(TPB);
    hipLaunchKernelGGL(node_kernel, grid, block, 0, stream,
                       pad0, sens, W1, b1v, W2, b2v, W3, b3v, sc, outp);
}

// Round 9
// 470.037 us; speedup vs baseline: 2.8483x; 1.0671x over previous
//
#include <hip/hip_runtime.h>

typedef __bf16 v8bf  __attribute__((ext_vector_type(8)));
typedef float  v4f   __attribute__((ext_vector_type(4)));
typedef int    v4i   __attribute__((ext_vector_type(4)));
typedef float  f32x2 __attribute__((ext_vector_type(2)));
union FR { v4i i4; v8bf bf; };

static constexpr int BATCH = 131072;
static constexpr int SENSN = 61;
static constexpr int NSTEP = 10;
static constexpr int TPB   = 256;
static constexpr int ROWP  = 72;   // ushorts/row: 144 B stride = 36 dw = 4 mod 32 banks -> 2-way (free)

#if __has_builtin(__builtin_amdgcn_exp2f)
#define EXP2(x) __builtin_amdgcn_exp2f(x)
#else
#define EXP2(x) exp2f(x)
#endif
#define RCP(x)  __builtin_amdgcn_rcpf(x)
#define FMA2(a,b,c) __builtin_elementwise_fma((a),(b),(c))   // -> v_pk_fma_f32

#define R32(M) \
  M(0) M(1) M(2) M(3) M(4) M(5) M(6) M(7) \
  M(8) M(9) M(10) M(11) M(12) M(13) M(14) M(15) \
  M(16) M(17) M(18) M(19) M(20) M(21) M(22) M(23) \
  M(24) M(25) M(26) M(27) M(28) M(29) M(30) M(31)

// pack two f32 -> dword of 2 bf16 (truncation): low16 = bf16(lo), hi16 = bf16(hi)
__device__ __forceinline__ unsigned pk(float hi, float lo) {
    return __builtin_amdgcn_perm(__float_as_uint(hi), __float_as_uint(lo), 0x07060302u);
}

__global__ void
__attribute__((amdgpu_flat_work_group_size(256, 256), amdgpu_waves_per_eu(2, 2)))
node_kernel(const float* __restrict__ pad0,
            const float* __restrict__ sens,
            const float* __restrict__ W1,
            const float* __restrict__ b1v,
            const float* __restrict__ W2,
            const float* __restrict__ b2v,
            const float* __restrict__ W3,
            const float* __restrict__ b3v,
            const float* __restrict__ scale_p,
            float* __restrict__ out)
{
    __shared__ ushort abuf[4 * 64 * ROWP];

    const int tid  = threadIdx.x;
    const int wv   = tid >> 6;
    const int lane = tid & 63;
    const int lo   = lane & 15;
    const int hh   = lane >> 4;
    const int hh0  = (lane >> 4) & 1;   // xor-16 bit
    const int hh1  = (lane >> 5) & 1;   // xor-32 bit
    const int b    = blockIdx.x * TPB + tid;

    ushort* __restrict__ aw = abuf + wv * 64 * ROWP;

    const float L     = 2.885390081777927f;  // 2*log2(e): exp(2x) = exp2(L*x)
    const float scale = scale_p[0];
    const float m2L   = -2.0f * L;
    const float m2s   = -2.0f * scale;
    const float h     = 0.1f;

    // ---- one-time: W2 fragments, used as MFMA A-operand (computes zz^T) ----
    FR b2f[4][2];
#pragma unroll
    for (int jb = 0; jb < 4; ++jb)
#pragma unroll
        for (int kc = 0; kc < 2; ++kc) {
            float w[8];
#pragma unroll
            for (int i = 0; i < 8; ++i)
                w[i] = W2[(hh*8 + i + 32*kc)*64 + lo + 16*jb];
            b2f[jb][kc].i4 = (v4i){ (int)pk(w[1],w[0]), (int)pk(w[3],w[2]),
                                    (int)pk(w[5],w[4]), (int)pk(w[7],w[6]) };
        }
    // layer-3 weights per lane, n-paired for pk_fma: j = 16jb+4hh+q
    f32x2 W3n01[4][4];   // {W3[j][0], W3[j][1]}
    float W3n2s[4][4];   //  W3[j][2]
#pragma unroll
    for (int jb = 0; jb < 4; ++jb)
#pragma unroll
        for (int q = 0; q < 4; ++q) {
            const int j = 16*jb + 4*hh + q;
            W3n01[jb][q] = (f32x2){ W3[j*3 + 0], W3[j*3 + 1] };
            W3n2s[jb][q] = W3[j*3 + 2];
        }
    // L-prescaled layer-2 bias, q-paired
    f32x2 b2lo[4], b2hi[4];
#pragma unroll
    for (int jb = 0; jb < 4; ++jb) {
        b2lo[jb] = (f32x2){ L*b2v[16*jb + 4*hh + 0], L*b2v[16*jb + 4*hh + 1] };
        b2hi[jb] = (f32x2){ L*b2v[16*jb + 4*hh + 2], L*b2v[16*jb + 4*hh + 3] };
    }
    const float b3L0 = L * b3v[0], b3L1 = L * b3v[1], b3L2 = L * b3v[2];

    const float* __restrict__ w1r0 = W1;          // row 0 (y0)
    const float* __restrict__ w1r1 = W1 + 64;     // row 1 (y1)
    const float* __restrict__ w1r2 = W1 + 128;    // row 2 (y2)
    const float* __restrict__ w1rt = W1 + 4096;   // row 64 (t)

    // ---- one-time: S' pairs = L*(b1 + sensory @ W1[3:64]) in named f32x2 VGPRs ----
#define SDECL(k) f32x2 s2_##k = *(const f32x2*)(b1v + 2*(k));
    R32(SDECL)
#undef SDECL
    {
        const float* __restrict__ srow = sens + (long)b * SENSN;
#pragma unroll 1
        for (int s = 0; s < SENSN; ++s) {
            const float xv = srow[s];
            const f32x2 xv2 = { xv, xv };
            const float* __restrict__ w = W1 + (3 + s) * 64;
#define SFMA(k) s2_##k = FMA2(xv2, *(const f32x2*)(w + 2*(k)), s2_##k);
            R32(SFMA)
#undef SFMA
        }
    }
    {
        const f32x2 L2 = { L, L };
#define SSC(k) s2_##k = s2_##k * L2;
        R32(SSC)
#undef SSC
    }

    float y0 = pad0[b*3 + 0];
    float y1 = pad0[b*3 + 1];
    float y2 = pad0[b*3 + 2];

    float k00=0,k01=0,k02=0, k10=0,k11=0,k12=0, k20=0,k21=0,k22=0,
          k30=0,k31=0,k32=0, k40=0,k41=0,k42=0;

#pragma unroll 1
    for (int step = 0; step < NSTEP; ++step) {
        const float t0 = (float)step * h;
#pragma unroll 1
        for (int st = 0; st < 6; ++st) {
            // ---- phase A: dopri5 stage combine (wave-uniform switch) ----
            float tt = t0, v0 = y0, v1 = y1, v2 = y2;
            switch (st) {
            case 0: break;
            case 1: {
                const float a21 = 0.2f;
                v0 = fmaf(h, a21*k00, y0); v1 = fmaf(h, a21*k01, y1); v2 = fmaf(h, a21*k02, y2);
                tt = t0 + 0.2f*h;
            } break;
            case 2: {
                const float a31 = 3.f/40.f, a32 = 9.f/40.f;
                v0 = fmaf(h, a31*k00 + a32*k10, y0);
                v1 = fmaf(h, a31*k01 + a32*k11, y1);
                v2 = fmaf(h, a31*k02 + a32*k12, y2);
                tt = t0 + 0.3f*h;
            } break;
            case 3: {
                const float a41 = 44.f/45.f, a42 = -56.f/15.f, a43 = 32.f/9.f;
                v0 = fmaf(h, a41*k00 + a42*k10 + a43*k20, y0);
                v1 = fmaf(h, a41*k01 + a42*k11 + a43*k21, y1);
                v2 = fmaf(h, a41*k02 + a42*k12 + a43*k22, y2);
                tt = t0 + 0.8f*h;
            } break;
            case 4: {
                const float a51 = 19372.f/6561.f, a52 = -25360.f/2187.f,
                            a53 = 64448.f/6561.f, a54 = -212.f/729.f;
                v0 = fmaf(h, a51*k00 + a52*k10 + a53*k20 + a54*k30, y0);
                v1 = fmaf(h, a51*k01 + a52*k11 + a53*k21 + a54*k31, y1);
                v2 = fmaf(h, a51*k02 + a52*k12 + a53*k22 + a54*k32, y2);
                tt = t0 + (8.f/9.f)*h;
            } break;
            default: {
                const float a61 = 9017.f/3168.f, a62 = -355.f/33.f,
                            a63 = 46732.f/5247.f, a64 = 49.f/176.f, a65 = -5103.f/18656.f;
                v0 = fmaf(h, a61*k00 + a62*k10 + a63*k20 + a64*k30 + a65*k40, y0);
                v1 = fmaf(h, a61*k01 + a62*k11 + a63*k21 + a64*k31 + a65*k41, y1);
                v2 = fmaf(h, a61*k02 + a62*k12 + a63*k22 + a64*k32 + a65*k42, y2);
                tt = t0 + h;
            } break;
            }
            const f32x2 v0p2 = { L*v0, L*v0 }, v1p2 = { L*v1, L*v1 },
                        v2p2 = { L*v2, L*v2 }, ttp2 = { L*tt, L*tt };

            // ---- phase B: layer1 rank-4 (pk_fma) + tanh (raw v_exp), stage bf16 ----
            unsigned pw[32];
#define L1P(k) { \
    f32x2 z2 = s2_##k; \
    z2 = FMA2(v0p2, *(const f32x2*)(w1r0 + 2*(k)), z2); \
    z2 = FMA2(v1p2, *(const f32x2*)(w1r1 + 2*(k)), z2); \
    z2 = FMA2(v2p2, *(const f32x2*)(w1r2 + 2*(k)), z2); \
    z2 = FMA2(ttp2, *(const f32x2*)(w1rt + 2*(k)), z2); \
    float ta = fmaf(m2L, RCP(EXP2(z2.x) + 1.0f), L); \
    float tb = fmaf(m2L, RCP(EXP2(z2.y) + 1.0f), L); \
    pw[k] = pk(tb, ta); }
            R32(L1P)
#undef L1P
            {
                v4i* __restrict__ dst = (v4i*)&aw[lane * ROWP];
#pragma unroll
                for (int w8 = 0; w8 < 8; ++w8)
                    dst[w8] = (v4i){ (int)pw[4*w8+0], (int)pw[4*w8+1],
                                     (int)pw[4*w8+2], (int)pw[4*w8+3] };
            }
            asm volatile("" ::: "memory");

            // ---- phases C/D/E fused per nb-block (acc live = 16 regs) ----
            const v4f z4 = {0.f, 0.f, 0.f, 0.f};
            f32x2 p01[4];            // accum for n=0,1
            float p2s[4];            // accum for n=2
#pragma unroll
            for (int nb = 0; nb < 4; ++nb) { p01[nb] = (f32x2){0.f, 0.f}; p2s[nb] = 0.f; }
#pragma unroll
            for (int nb = 0; nb < 4; ++nb) {
                FR a0, a1;
                a0.i4 = *(const v4i*)&aw[(lo + 16*nb)*ROWP + hh*8];
                a1.i4 = *(const v4i*)&aw[(lo + 16*nb)*ROWP + hh*8 + 32];
                v4f acc[4];
#pragma unroll
                for (int jb = 0; jb < 4; ++jb) {
                    v4f t = __builtin_amdgcn_mfma_f32_16x16x32_bf16(b2f[jb][0].bf, a0.bf, z4, 0, 0, 0);
                    acc[jb] = __builtin_amdgcn_mfma_f32_16x16x32_bf16(b2f[jb][1].bf, a1.bf, t, 0, 0, 0);
                }
#pragma unroll
                for (int jb = 0; jb < 4; ++jb) {
                    f32x2 zlo = __builtin_shufflevector(acc[jb], acc[jb], 0, 1) + b2lo[jb];
                    f32x2 zhi = __builtin_shufflevector(acc[jb], acc[jb], 2, 3) + b2hi[jb];
                    float zq[4] = { zlo.x, zlo.y, zhi.x, zhi.y };
#pragma unroll
                    for (int q = 0; q < 4; ++q) {
                        float t2 = fmaf(m2L, RCP(EXP2(zq[q]) + 1.0f), L);   // L*tanh
                        const f32x2 ts = { t2, t2 };
                        p01[nb] = FMA2(ts, W3n01[jb][q], p01[nb]);
                        p2s[nb] = fmaf(t2, W3n2s[jb][q], p2s[nb]);
                    }
                }
            }
            asm volatile("" ::: "memory");

            float p[4][3];
#pragma unroll
            for (int nb = 0; nb < 4; ++nb) {
                p[nb][0] = p01[nb].x; p[nb][1] = p01[nb].y; p[nb][2] = p2s[nb];
            }

            // ---- reduce-scatter butterfly: lane d ends with o for batch row d ----
            float q2[2][3];
#pragma unroll
            for (int j2 = 0; j2 < 2; ++j2)
#pragma unroll
                for (int n = 0; n < 3; ++n) {
                    float keep = hh1 ? p[2+j2][n] : p[j2][n];
                    float send = hh1 ? p[j2][n]   : p[2+j2][n];
                    q2[j2][n] = keep + __shfl_xor(send, 32, 64);
                }
            float o0, o1, o2;
            {
                float keep0 = hh0 ? q2[1][0] : q2[0][0];
                float send0 = hh0 ? q2[0][0] : q2[1][0];
                o0 = keep0 + __shfl_xor(send0, 16, 64);
                float keep1 = hh0 ? q2[1][1] : q2[0][1];
                float send1 = hh0 ? q2[0][1] : q2[1][1];
                o1 = keep1 + __shfl_xor(send1, 16, 64);
                float keep2 = hh0 ? q2[1][2] : q2[0][2];
                float send2 = hh0 ? q2[0][2] : q2[1][2];
                o2 = keep2 + __shfl_xor(send2, 16, 64);
            }

            // ---- final tanh*scale, RK bookkeeping ----
            const float r0 = fmaf(m2s, RCP(EXP2(o0 + b3L0) + 1.0f), scale);
            const float r1 = fmaf(m2s, RCP(EXP2(o1 + b3L1) + 1.0f), scale);
            const float r2 = fmaf(m2s, RCP(EXP2(o2 + b3L2) + 1.0f), scale);

            switch (st) {
            case 0: k00=r0; k01=r1; k02=r2; break;
            case 1: k10=r0; k11=r1; k12=r2; break;
            case 2: k20=r0; k21=r1; k22=r2; break;
            case 3: k30=r0; k31=r1; k32=r2; break;
            case 4: k40=r0; k41=r1; k42=r2; break;
            default: {
                const float c1 = 35.f/384.f,  c3c = 500.f/1113.f,
                            c4 = 125.f/192.f, c5 = -2187.f/6784.f, c6 = 11.f/84.f;
                y0 = fmaf(h, c1*k00 + c3c*k20 + c4*k30 + c5*k40 + c6*r0, y0);
                y1 = fmaf(h, c1*k01 + c3c*k21 + c4*k31 + c5*k41 + c6*r1, y1);
                y2 = fmaf(h, c1*k02 + c3c*k22 + c4*k32 + c5*k42 + c6*r2, y2);
            } break;
            }
        }
    }

    out[b*3 + 0] = y0;
    out[b*3 + 1] = y1;
    out[b*3 + 2] = y2;
}

extern "C" void kernel_launch(void* const* d_in, const int* in_sizes, int n_in,
                              void* d_out, int out_size, void* d_ws, size_t ws_size,
                              hipStream_t stream) {
    const float* pad0 = (const float*)d_in[0];
    const float* sens = (const float*)d_in[1];
    const float* W1   = (const float*)d_in[2];
    const float* b1v  = (const float*)d_in[3];
    const float* W2   = (const float*)d_in[4];
    const float* b2v  = (const float*)d_in[5];
    const float* W3   = (const float*)d_in[6];
    const float* b3v  = (const float*)d_in[7];
    const float* sc   = (const float*)d_in[8];
    float* outp = (float*)d_out;

    dim3 grid(BATCH / TPB), block(TPB);
    hipLaunchKernelGGL(node_kernel, grid, block, 0, stream,
                       pad0, sens, W1, b1v, W2, b2v, W3, b3v, sc, outp);
}